// Round 1
// baseline (282.553 us; speedup 1.0000x reference)
//
#include <hip/hip_runtime.h>
#include <math.h>

// PCATemplateMap: x (64,2048,19,19) f32, templates (10,19,19) f32
// outputs: mask (64,1,19,19) then v (64,10), concatenated flat.
//
// Pipeline:
//  k1: per (b, c-block) compute Q[t,c] = <T_t, x[b,c,:]>, accumulate
//      S1[t] = sum_c Q, S2[t,s] = sum_c Q_t Q_s   -> partial sums in d_ws
//  k2: per batch: reduce partials, D = S2 - S1 S1^T / C, then a faithful
//      fp32 port of LAPACK ssyevd (ssytd2 + ssteqr 'I' + sormtr) to match
//      numpy's eigenvector SIGN; v = Z[:, 9] (largest eig), mask = v @ Bt.

#define NB   64
#define NC   2048
#define NHW  361
#define NTMP 10

// ---------------- unaligned float4 load (row base is only 4B-aligned) ----
struct f4 { float x, y, z, w; };
__device__ inline f4 load4u(const float* p){
    f4 r;
    __builtin_memcpy(&r, p, 16);
    return r;
}

// ======================= Kernel 1: partial S1/S2 ==========================
__global__ __launch_bounds__(256) void k1_partials(
        const float* __restrict__ x, const float* __restrict__ tmpl,
        float* __restrict__ partial, int cblk, int cpb, int citer)
{
    __shared__ __align__(16) float Tl[NTMP][368];   // padded row stride, 16B aligned
    __shared__ float red[64][66];
    const int tid = threadIdx.x;

    for (int idx = tid; idx < NTMP*368; idx += 256){
        int t = idx / 368, i = idx - t*368;
        Tl[t][i] = (i < NHW) ? tmpl[t*NHW + i] : 0.f;
    }
    __syncthreads();

    const int b  = blockIdx.x / cblk;
    const int cb = blockIdx.x - b*cblk;
    const int g  = tid >> 2;     // 4 lanes cooperate on one channel
    const int iq = tid & 3;

    float S1[NTMP];
    float S2[55];
    #pragma unroll
    for (int t = 0; t < NTMP; t++) S1[t] = 0.f;
    #pragma unroll
    for (int k = 0; k < 55; k++) S2[k] = 0.f;

    for (int ci = 0; ci < citer; ci++){
        const int c = cb*cpb + ci*64 + g;
        const float* xrow = x + (size_t)(b*NC + c)*NHW;
        float acc[NTMP];
        #pragma unroll
        for (int t = 0; t < NTMP; t++) acc[t] = 0.f;

        // i in [0,352): 22 blocks of 16, lane iq covers [blk*16+iq*4, +4)
        for (int blk = 0; blk < 22; blk++){
            const int i0 = blk*16 + iq*4;
            f4 xv = load4u(xrow + i0);
            #pragma unroll
            for (int t = 0; t < NTMP; t++){
                const float4 tv = *reinterpret_cast<const float4*>(&Tl[t][i0]);
                acc[t] += xv.x*tv.x + xv.y*tv.y + xv.z*tv.z + xv.w*tv.w;
            }
        }
        // tail i = 352..360
        for (int i = 352 + iq; i < NHW; i += 4){
            const float xv = xrow[i];
            #pragma unroll
            for (int t = 0; t < NTMP; t++) acc[t] += xv * Tl[t][i];
        }
        // reduce Q over the 4 lanes of the group
        #pragma unroll
        for (int t = 0; t < NTMP; t++){
            acc[t] += __shfl_xor(acc[t], 1, 64);
            acc[t] += __shfl_xor(acc[t], 2, 64);
        }
        if (iq == 0){
            int k = 0;
            #pragma unroll
            for (int t = 0; t < NTMP; t++){
                S1[t] += acc[t];
                #pragma unroll
                for (int s = t; s < NTMP; s++){
                    S2[k] += acc[t]*acc[s];
                    k++;
                }
            }
        }
    }

    if (iq == 0){
        #pragma unroll
        for (int t = 0; t < NTMP; t++) red[g][t] = S1[t];
        #pragma unroll
        for (int k = 0; k < 55; k++) red[g][NTMP + k] = S2[k];
    }
    __syncthreads();
    if (tid < 65){
        float s = 0.f;
        for (int g2 = 0; g2 < 64; g2++) s += red[g2][tid];
        partial[(size_t)blockIdx.x*65 + tid] = s;
    }
}

// =================== faithful fp32 LAPACK helpers =========================
__device__ inline float f_sign(float a, float b){
    return (b >= 0.f) ? fabsf(a) : -fabsf(a);     // Fortran SIGN(a,b)
}

__device__ inline float slapy2(float xx, float yy){
#pragma clang fp contract(off)
    float xa = fabsf(xx), ya = fabsf(yy);
    float w = fmaxf(xa, ya), z = fminf(xa, ya);
    if (z == 0.f) return w;
    float q = z / w;
    return w * sqrtf(1.f + q*q);
}

// LAPACK >= 3.10 slartg convention (c >= 0). If signs come back flipped on
// hardware, switch to the pre-3.10 convention.
__device__ inline void slartg(float f, float g, float* cs, float* sn, float* rr){
#pragma clang fp contract(off)
    const float safmin = 0x1.0p-126f;
    const float safmax = 0x1.0p+126f;
    const float rtmin  = 0x1.0p-63f;
    const float rtmax  = 6.5211589e18f;  // sqrt(safmax/2)
    float f1 = fabsf(f), g1 = fabsf(g);
    if (g == 0.f){ *cs = 1.f; *sn = 0.f; *rr = f; }
    else if (f == 0.f){
        *cs = 0.f;
        *sn = (g >= 0.f) ? 1.f : -1.f;
        *rr = g1;
    } else {
        if (f1 > rtmin && f1 < rtmax && g1 > rtmin && g1 < rtmax){
            float d = sqrtf(f*f + g*g);
            *cs = f1 / d;
            *rr = (f >= 0.f) ? d : -d;
            *sn = g / (*rr);
        } else {
            float u = fminf(safmax, fmaxf(safmin, fmaxf(f1, g1)));
            float fs = f/u, gs = g/u;
            float d = sqrtf(fs*fs + gs*gs);
            *cs = fabsf(fs)/d;
            float r0 = (f >= 0.f) ? d : -d;
            *sn = gs / r0;
            *rr = r0 * u;
        }
    }
}

__device__ inline void slaev2(float a, float b, float c,
                              float* rt1, float* rt2, float* cs1, float* sn1){
#pragma clang fp contract(off)
    float sm = a + c;
    float df = a - c;
    float adf = fabsf(df);
    float tb = b + b;
    float ab = fabsf(tb);
    float acmx, acmn;
    if (fabsf(a) > fabsf(c)){ acmx = a; acmn = c; } else { acmx = c; acmn = a; }
    float rt;
    if (adf > ab){ float q = ab/adf; rt = adf*sqrtf(1.f + q*q); }
    else if (adf < ab){ float q = adf/ab; rt = ab*sqrtf(1.f + q*q); }
    else { rt = ab*sqrtf(2.f); }
    int sgn1;
    if (sm < 0.f){
        *rt1 = 0.5f*(sm - rt); sgn1 = -1;
        *rt2 = (acmx / *rt1)*acmn - (b / *rt1)*b;
    } else if (sm > 0.f){
        *rt1 = 0.5f*(sm + rt); sgn1 = 1;
        *rt2 = (acmx / *rt1)*acmn - (b / *rt1)*b;
    } else {
        *rt1 = 0.5f*rt; *rt2 = -0.5f*rt; sgn1 = 1;
    }
    float cs; int sgn2;
    if (df >= 0.f){ cs = df + rt; sgn2 = 1; }
    else { cs = df - rt; sgn2 = -1; }
    float acs = fabsf(cs);
    if (acs > ab){
        float ct = -tb/cs;
        *sn1 = 1.f/sqrtf(1.f + ct*ct);
        *cs1 = ct * (*sn1);
    } else {
        if (ab == 0.f){ *cs1 = 1.f; *sn1 = 0.f; }
        else {
            float tn = -cs/tb;
            *cs1 = 1.f/sqrtf(1.f + tn*tn);
            *sn1 = tn * (*cs1);
        }
    }
    if (sgn1 == sgn2){
        float tn = *cs1;
        *cs1 = -(*sn1);
        *sn1 = tn;
    }
}

#define A_(i,j) Aa[((j)-1)*10 + ((i)-1)]
#define Z_(i,j) Zz[((j)-1)*10 + ((i)-1)]

// ssyevd('V','L') for n=10: ssytd2(L) + ssteqr('I') + sormtr('L','L','N')
__device__ void eig10(float* Aa, float* Zz, float* dd, float* ee,
                      float* tt, float* wk, float* px)
{
#pragma clang fp contract(off)
    const int n = 10;

    // ---------------- ssytd2 (lower) ----------------
    for (int i = 1; i <= n-1; i++){
        float alpha = A_(i+1, i);
        float ssq = 0.f;
        for (int k = i+2; k <= n; k++){ float v = A_(k,i); ssq += v*v; }
        float xnorm = sqrtf(ssq);
        float taui;
        if (xnorm == 0.f){
            taui = 0.f;
        } else {
            float beta = -f_sign(slapy2(alpha, xnorm), alpha);
            taui = (beta - alpha) / beta;
            float sc = 1.f / (alpha - beta);
            for (int k = i+2; k <= n; k++) A_(k,i) *= sc;
            alpha = beta;
        }
        ee[i] = alpha;
        if (taui != 0.f){
            A_(i+1, i) = 1.f;
            int n2 = n - i;
            // ssymv 'L': px = taui * A(i+1:n,i+1:n) * v (LAPACK loop order)
            for (int j = 1; j <= n2; j++) px[j] = 0.f;
            for (int j = 1; j <= n2; j++){
                float temp1 = taui * A_(i+j, i);
                float temp2 = 0.f;
                px[j] = px[j] + temp1 * A_(i+j, i+j);
                for (int ii2 = j+1; ii2 <= n2; ii2++){
                    px[ii2] = px[ii2] + temp1 * A_(i+ii2, i+j);
                    temp2   = temp2   + A_(i+ii2, i+j) * A_(i+ii2, i);
                }
                px[j] = px[j] + taui * temp2;
            }
            float dot = 0.f;
            for (int j = 1; j <= n2; j++) dot = dot + px[j] * A_(i+j, i);
            float alpha2 = -0.5f * taui * dot;
            for (int j = 1; j <= n2; j++) px[j] = px[j] + alpha2 * A_(i+j, i);
            // ssyr2 'L', alpha = -1
            for (int j = 1; j <= n2; j++){
                float xj = A_(i+j, i);
                float yj = px[j];
                if (xj != 0.f || yj != 0.f){
                    float temp1 = -yj;
                    float temp2 = -xj;
                    for (int ii2 = j; ii2 <= n2; ii2++){
                        A_(i+ii2, i+j) = A_(i+ii2, i+j)
                                       + A_(i+ii2, i)*temp1 + px[ii2]*temp2;
                    }
                }
            }
            A_(i+1, i) = ee[i];
        }
        dd[i] = A_(i, i);
        tt[i] = taui;
    }
    dd[n] = A_(n, n);

    // Z = I
    for (int j = 1; j <= n; j++)
        for (int i2 = 1; i2 <= n; i2++)
            Z_(i2, j) = (i2 == j) ? 1.f : 0.f;

    // ---------------- ssteqr 'I' ----------------
    const float eps    = 0x1.0p-24f;
    const float eps2   = 0x1.0p-48f;
    const float safmin = 0x1.0p-126f;
    const int nmaxit = n * 30;
    int jtot = 0;
    int l1 = 1;
    bool conv_fail = false;

    while (true){
        if (l1 > n) break;
        if (l1 > 1) ee[l1-1] = 0.f;
        int m = n;
        if (l1 <= n-1){
            for (m = l1; m <= n-1; m++){
                float tst = fabsf(ee[m]);
                if (tst == 0.f) break;
                if (tst <= (sqrtf(fabsf(dd[m])) * sqrtf(fabsf(dd[m+1]))) * eps){
                    ee[m] = 0.f;
                    break;
                }
            }
        }
        int l = l1;
        int lsv = l;
        int lend = m;
        int lendsv = lend;
        l1 = m + 1;
        if (lend == l) continue;

        float anorm = 0.f;
        for (int k = l; k <= lend; k++)   anorm = fmaxf(anorm, fabsf(dd[k]));
        for (int k = l; k <= lend-1; k++) anorm = fmaxf(anorm, fabsf(ee[k]));
        if (anorm == 0.f) continue;
        // (sstreqr block scaling skipped: D-scale ~1e5..1e6, safely in range)

        if (fabsf(dd[lend]) < fabsf(dd[l])){
            lend = lsv;
            l = lendsv;
        }

        if (lend > l){
            // -------- QL --------
            while (true){
                int mq = lend;
                if (l != lend){
                    for (int t2 = l; t2 <= lend-1; t2++){
                        float ev = fabsf(ee[t2]);
                        if (ev*ev <= (eps2*fabsf(dd[t2]))*fabsf(dd[t2+1]) + safmin){
                            mq = t2; break;
                        }
                    }
                }
                if (mq < lend) ee[mq] = 0.f;
                float p = dd[l];
                if (mq == l){
                    dd[l] = p;
                    l = l + 1;
                    if (l <= lend) continue;
                    break;
                }
                if (mq == l+1){
                    float rt1, rt2, cc, ss;
                    slaev2(dd[l], ee[l], dd[l+1], &rt1, &rt2, &cc, &ss);
                    wk[l] = cc; wk[n-1+l] = ss;
                    for (int r2 = 1; r2 <= n; r2++){
                        float temp = Z_(r2, l+1);
                        Z_(r2, l+1) = cc*temp - ss*Z_(r2, l);
                        Z_(r2, l)   = ss*temp + cc*Z_(r2, l);
                    }
                    dd[l] = rt1; dd[l+1] = rt2; ee[l] = 0.f;
                    l += 2;
                    if (l <= lend) continue;
                    break;
                }
                if (jtot == nmaxit) break;
                jtot++;
                float g = (dd[l+1] - p) / (2.f * ee[l]);
                float r = slapy2(g, 1.f);
                g = dd[mq] - p + (ee[l] / (g + f_sign(r, g)));
                float ss = 1.f, cc = 1.f;
                p = 0.f;
                for (int i2 = mq-1; i2 >= l; i2--){
                    float ff = ss * ee[i2];
                    float bb = cc * ee[i2];
                    slartg(g, ff, &cc, &ss, &r);
                    if (i2 != mq-1) ee[i2+1] = r;
                    g = dd[i2+1] - p;
                    r = (dd[i2] - g)*ss + 2.f*cc*bb;
                    p = ss*r;
                    dd[i2+1] = g + p;
                    g = cc*r - bb;
                    wk[i2] = cc;
                    wk[n-1+i2] = -ss;
                }
                // slasr 'R','V','B'
                for (int jj = mq-1; jj >= l; jj--){
                    float ct = wk[jj], st = wk[n-1+jj];
                    if (ct != 1.f || st != 0.f){
                        for (int r2 = 1; r2 <= n; r2++){
                            float temp = Z_(r2, jj+1);
                            Z_(r2, jj+1) = ct*temp - st*Z_(r2, jj);
                            Z_(r2, jj)   = st*temp + ct*Z_(r2, jj);
                        }
                    }
                }
                dd[l] = dd[l] - p;
                ee[l] = g;
            }
        } else {
            // -------- QR --------
            while (true){
                int mq = lend;
                if (l != lend){
                    for (int t2 = l; t2 >= lend+1; t2--){
                        float ev = fabsf(ee[t2-1]);
                        if (ev*ev <= (eps2*fabsf(dd[t2]))*fabsf(dd[t2-1]) + safmin){
                            mq = t2; break;
                        }
                    }
                }
                if (mq > lend) ee[mq-1] = 0.f;
                float p = dd[l];
                if (mq == l){
                    dd[l] = p;
                    l = l - 1;
                    if (l >= lend) continue;
                    break;
                }
                if (mq == l-1){
                    float rt1, rt2, cc, ss;
                    slaev2(dd[l-1], ee[l-1], dd[l], &rt1, &rt2, &cc, &ss);
                    wk[mq] = cc; wk[n-1+mq] = ss;
                    for (int r2 = 1; r2 <= n; r2++){
                        float temp = Z_(r2, l);
                        Z_(r2, l)   = cc*temp - ss*Z_(r2, l-1);
                        Z_(r2, l-1) = ss*temp + cc*Z_(r2, l-1);
                    }
                    dd[l-1] = rt1; dd[l] = rt2; ee[l-1] = 0.f;
                    l -= 2;
                    if (l >= lend) continue;
                    break;
                }
                if (jtot == nmaxit) break;
                jtot++;
                float g = (dd[l-1] - p) / (2.f * ee[l-1]);
                float r = slapy2(g, 1.f);
                g = dd[mq] - p + (ee[l-1] / (g + f_sign(r, g)));
                float ss = 1.f, cc = 1.f;
                p = 0.f;
                for (int i2 = mq; i2 <= l-1; i2++){
                    float ff = ss * ee[i2];
                    float bb = cc * ee[i2];
                    slartg(g, ff, &cc, &ss, &r);
                    if (i2 != mq) ee[i2-1] = r;
                    g = dd[i2] - p;
                    r = (dd[i2+1] - g)*ss + 2.f*cc*bb;
                    p = ss*r;
                    dd[i2] = g + p;
                    g = cc*r - bb;
                    wk[i2] = cc;
                    wk[n-1+i2] = ss;
                }
                // slasr 'R','V','F'
                for (int jj = mq; jj <= l-1; jj++){
                    float ct = wk[jj], st = wk[n-1+jj];
                    if (ct != 1.f || st != 0.f){
                        for (int r2 = 1; r2 <= n; r2++){
                            float temp = Z_(r2, jj+1);
                            Z_(r2, jj+1) = ct*temp - st*Z_(r2, jj);
                            Z_(r2, jj)   = st*temp + ct*Z_(r2, jj);
                        }
                    }
                }
                dd[l] = dd[l] - p;
                ee[l-1] = g;
            }
        }
        if (jtot < nmaxit) continue;
        conv_fail = true;
        break;
    }

    // ---------------- sort (selection, swap columns) ----------------
    if (!conv_fail){
        for (int ii2 = 2; ii2 <= n; ii2++){
            int i2 = ii2 - 1;
            int k = i2;
            float p = dd[i2];
            for (int j = ii2; j <= n; j++){
                if (dd[j] < p){ k = j; p = dd[j]; }
            }
            if (k != i2){
                dd[k] = dd[i2];
                dd[i2] = p;
                for (int r2 = 1; r2 <= n; r2++){
                    float t2 = Z_(r2, i2); Z_(r2, i2) = Z_(r2, k); Z_(r2, k) = t2;
                }
            }
        }
    }

    // ---------------- sormtr 'L','L','N': Z := H(1)..H(n-1) Z -------------
    for (int i = n-1; i >= 1; i--){
        float taui = tt[i];
        if (taui == 0.f) continue;
        for (int j = 1; j <= n; j++){
            float s1 = Z_(i+1, j);
            for (int r2 = i+2; r2 <= n; r2++) s1 = s1 + A_(r2, i) * Z_(r2, j);
            s1 = taui * s1;
            Z_(i+1, j) = Z_(i+1, j) - s1;
            for (int r2 = i+2; r2 <= n; r2++) Z_(r2, j) = Z_(r2, j) - A_(r2, i) * s1;
        }
    }
}

// ======================= Kernel 2: D, eigh, outputs =======================
__global__ __launch_bounds__(128) void k2_eig(
        const float* __restrict__ partial, const float* __restrict__ tmpl,
        float* __restrict__ out, int cblk)
{
    __shared__ float SS[65];
    __shared__ float Aa[100];
    __shared__ float Zz[100];
    __shared__ float dd[11], ee[11], tt[11], wk[20], px[11];
    __shared__ float vout[NTMP];
    const int tid = threadIdx.x;
    const int b = blockIdx.x;

    if (tid < 65){
        float s = 0.f;
        for (int p = 0; p < cblk; p++)
            s += partial[(size_t)(b*cblk + p)*65 + tid];
        SS[tid] = s;
    }
    __syncthreads();

    // D[t][s] = S2[t,s] - S1[t]*S1[s]/C   (exactly symmetric)
    if (tid < 100){
        int t = tid % 10, s2 = tid / 10;
        int lo = t < s2 ? t : s2, hi = t < s2 ? s2 : t;
        int idx = 10*lo - (lo*(lo-1))/2 + (hi - lo);
        float val = SS[10 + idx] - SS[t]*SS[s2]*(1.0f/2048.0f);
        Aa[s2*10 + t] = val;   // col-major, symmetric
    }
    __syncthreads();

    if (tid == 0){
        eig10(Aa, Zz, dd, ee, tt, wk, px);
        for (int t = 0; t < NTMP; t++){
            float vv = Zz[9*10 + t];            // Z(:,10) = top eigenvector
            vout[t] = vv;
            out[NB*NHW + b*NTMP + t] = vv;      // v output
        }
    }
    __syncthreads();

    for (int i = tid; i < NHW; i += 128){
        float m2 = 0.f;
        #pragma unroll
        for (int t = 0; t < NTMP; t++) m2 += vout[t] * tmpl[t*NHW + i];
        out[b*NHW + i] = m2;                    // mask output
    }
}

// ============================== launcher ==================================
extern "C" void kernel_launch(void* const* d_in, const int* in_sizes, int n_in,
                              void* d_out, int out_size, void* d_ws, size_t ws_size,
                              hipStream_t stream)
{
    const float* x    = (const float*)d_in[0];
    const float* tmpl = (const float*)d_in[1];
    float* out = (float*)d_out;
    float* partial = (float*)d_ws;

    int cblk = 16;
    if (ws_size < (size_t)NB*16*65*sizeof(float)) cblk = 4;
    if (ws_size < (size_t)NB*4*65*sizeof(float))  cblk = 1;
    const int cpb = NC / cblk;        // channels per workgroup
    const int citer = cpb / 64;       // channel iterations per workgroup

    k1_partials<<<dim3(NB*cblk), dim3(256), 0, stream>>>(x, tmpl, partial,
                                                         cblk, cpb, citer);
    k2_eig<<<dim3(NB), dim3(128), 0, stream>>>(partial, tmpl, out, cblk);
}

// Round 2
// 142.654 us; speedup vs baseline: 1.9807x; 1.9807x over previous
//
#include <hip/hip_runtime.h>
#include <math.h>

// PCATemplateMap: x (64,2048,19,19) f32, templates (10,19,19) f32
// outputs: mask (64,1,19,19) then v (64,10), concatenated flat.
//
//  k1: thread owns NCPT channels; Q[t] accumulated in registers with template
//      chunks broadcast from LDS; per-thread S1/S2 -> wave shuffle reduce ->
//      block reduce -> partial sums in d_ws.
//  k2: one WAVE per batch. D = S2 - S1 S1^T / C, then faithful fp32 LAPACK
//      ssyevd (ssytd2 + ssteqr 'I' + argmax + single-column sormtr). Scalar
//      chains run redundantly on all lanes; O(n^2) parts lane-parallel with
//      bit-identical per-element arithmetic order.

#define NB   64
#define NC   2048
#define NHW  361
#define NTMP 10

struct f4 { float x, y, z, w; };
__device__ inline f4 load4u(const float* p){
    f4 r;
    __builtin_memcpy(&r, p, 16);
    return r;
}

// ======================= Kernel 1: partial S1/S2 ==========================
template<int NCPT>
__global__ __launch_bounds__(256) void k1_partials(
        const float* __restrict__ x, const float* __restrict__ tmpl,
        float* __restrict__ partial)
{
    __shared__ __align__(16) float Tl[NTMP][364];   // 16B-aligned rows (364*4=1456)
    __shared__ float red[4][65];
    const int tid = threadIdx.x;
    for (int idx = tid; idx < NTMP*364; idx += 256){
        int t = idx / 364, i = idx - t*364;
        Tl[t][i] = (i < NHW) ? tmpl[t*NHW + i] : 0.f;
    }
    __syncthreads();

    constexpr int CPB = 256*NCPT;          // channels per block
    const int CBLK = NC / CPB;
    const int b  = blockIdx.x / CBLK;
    const int cb = blockIdx.x % CBLK;
    const int c0 = cb*CPB + tid;

    const float* xr[NCPT];
    #pragma unroll
    for (int s = 0; s < NCPT; s++)
        xr[s] = x + ((size_t)b*NC + c0 + s*256)*NHW;

    float acc[NCPT][NTMP];
    #pragma unroll
    for (int s = 0; s < NCPT; s++)
        #pragma unroll
        for (int t = 0; t < NTMP; t++) acc[s][t] = 0.f;

    // 90 chunks of 4 + scalar tail (361 = 90*4 + 1)
    #pragma unroll 6
    for (int ch = 0; ch < 90; ch++){
        const int i0 = ch*4;
        f4 xv[NCPT];
        #pragma unroll
        for (int s = 0; s < NCPT; s++) xv[s] = load4u(xr[s] + i0);
        #pragma unroll
        for (int t = 0; t < NTMP; t++){
            const float4 tv = *reinterpret_cast<const float4*>(&Tl[t][i0]);
            #pragma unroll
            for (int s = 0; s < NCPT; s++)
                acc[s][t] += xv[s].x*tv.x + xv[s].y*tv.y + xv[s].z*tv.z + xv[s].w*tv.w;
        }
    }
    #pragma unroll
    for (int s = 0; s < NCPT; s++){
        const float xt = xr[s][360];
        #pragma unroll
        for (int t = 0; t < NTMP; t++) acc[s][t] += xt * Tl[t][360];
    }

    // per-thread S contributions
    float S[65];
    #pragma unroll
    for (int t = 0; t < NTMP; t++){
        float v = 0.f;
        #pragma unroll
        for (int s = 0; s < NCPT; s++) v += acc[s][t];
        S[t] = v;
    }
    {
        int k = NTMP;
        #pragma unroll
        for (int t = 0; t < NTMP; t++){
            #pragma unroll
            for (int u = t; u < NTMP; u++){
                float v = 0.f;
                #pragma unroll
                for (int s = 0; s < NCPT; s++) v += acc[s][t]*acc[s][u];
                S[k++] = v;
            }
        }
    }
    // wave shuffle reduce (width 64)
    #pragma unroll
    for (int j = 0; j < 65; j++){
        float v = S[j];
        v += __shfl_xor(v, 32);
        v += __shfl_xor(v, 16);
        v += __shfl_xor(v, 8);
        v += __shfl_xor(v, 4);
        v += __shfl_xor(v, 2);
        v += __shfl_xor(v, 1);
        S[j] = v;
    }
    const int wid = tid >> 6, ln = tid & 63;
    if (ln == 0){
        #pragma unroll
        for (int j = 0; j < 65; j++) red[wid][j] = S[j];
    }
    __syncthreads();
    if (tid < 65){
        float v = red[0][tid] + red[1][tid] + red[2][tid] + red[3][tid];
        partial[(size_t)blockIdx.x*65 + tid] = v;
    }
}

// =================== faithful fp32 LAPACK helpers =========================
__device__ inline float f_sign(float a, float b){
    return (b >= 0.f) ? fabsf(a) : -fabsf(a);     // Fortran SIGN(a,b)
}

__device__ inline float slapy2(float xx, float yy){
#pragma clang fp contract(off)
    float xa = fabsf(xx), ya = fabsf(yy);
    float w = fmaxf(xa, ya), z = fminf(xa, ya);
    if (z == 0.f) return w;
    float q = z / w;
    return w * sqrtf(1.f + q*q);
}

// LAPACK >= 3.10 slartg convention (c >= 0).
__device__ inline void slartg(float f, float g, float* cs, float* sn, float* rr){
#pragma clang fp contract(off)
    const float safmin = 0x1.0p-126f;
    const float safmax = 0x1.0p+126f;
    const float rtmin  = 0x1.0p-63f;
    const float rtmax  = 6.5211589e18f;  // sqrt(safmax/2)
    float f1 = fabsf(f), g1 = fabsf(g);
    if (g == 0.f){ *cs = 1.f; *sn = 0.f; *rr = f; }
    else if (f == 0.f){
        *cs = 0.f;
        *sn = (g >= 0.f) ? 1.f : -1.f;
        *rr = g1;
    } else {
        if (f1 > rtmin && f1 < rtmax && g1 > rtmin && g1 < rtmax){
            float d = sqrtf(f*f + g*g);
            *cs = f1 / d;
            *rr = (f >= 0.f) ? d : -d;
            *sn = g / (*rr);
        } else {
            float u = fminf(safmax, fmaxf(safmin, fmaxf(f1, g1)));
            float fs = f/u, gs = g/u;
            float d = sqrtf(fs*fs + gs*gs);
            *cs = fabsf(fs)/d;
            float r0 = (f >= 0.f) ? d : -d;
            *sn = gs / r0;
            *rr = r0 * u;
        }
    }
}

__device__ inline void slaev2(float a, float b, float c,
                              float* rt1, float* rt2, float* cs1, float* sn1){
#pragma clang fp contract(off)
    float sm = a + c;
    float df = a - c;
    float adf = fabsf(df);
    float tb = b + b;
    float ab = fabsf(tb);
    float acmx, acmn;
    if (fabsf(a) > fabsf(c)){ acmx = a; acmn = c; } else { acmx = c; acmn = a; }
    float rt;
    if (adf > ab){ float q = ab/adf; rt = adf*sqrtf(1.f + q*q); }
    else if (adf < ab){ float q = adf/ab; rt = ab*sqrtf(1.f + q*q); }
    else { rt = ab*sqrtf(2.f); }
    int sgn1;
    if (sm < 0.f){
        *rt1 = 0.5f*(sm - rt); sgn1 = -1;
        *rt2 = (acmx / *rt1)*acmn - (b / *rt1)*b;
    } else if (sm > 0.f){
        *rt1 = 0.5f*(sm + rt); sgn1 = 1;
        *rt2 = (acmx / *rt1)*acmn - (b / *rt1)*b;
    } else {
        *rt1 = 0.5f*rt; *rt2 = -0.5f*rt; sgn1 = 1;
    }
    float cs; int sgn2;
    if (df >= 0.f){ cs = df + rt; sgn2 = 1; }
    else { cs = df - rt; sgn2 = -1; }
    float acs = fabsf(cs);
    if (acs > ab){
        float ct = -tb/cs;
        *sn1 = 1.f/sqrtf(1.f + ct*ct);
        *cs1 = ct * (*sn1);
    } else {
        if (ab == 0.f){ *cs1 = 1.f; *sn1 = 0.f; }
        else {
            float tn = -cs/tb;
            *cs1 = 1.f/sqrtf(1.f + tn*tn);
            *sn1 = tn * (*cs1);
        }
    }
    if (sgn1 == sgn2){
        float tn = *cs1;
        *cs1 = -(*sn1);
        *sn1 = tn;
    }
}

#define A_(i,j) Aa[((j)-1)*10 + ((i)-1)]
#define Z_(i,j) Zz[((j)-1)*10 + ((i)-1)]

// wave-cooperative ssyevd('V','L') n=10.
// Scalar chains: all 64 lanes redundantly (identical values -> identical LDS
// writes, benign). O(n^2) parts: lane-parallel, per-element arithmetic order
// identical to the serial LAPACK loops.
__device__ void eig10_wave(int lane, float* Aa, float* Zz, float* dd, float* ee,
                           float* tt, float* wk, float* px, float* vcol)
{
#pragma clang fp contract(off)
    const int n = 10;

    // ---------------- ssytd2 (lower) ----------------
    for (int i = 1; i <= n-1; i++){
        float alpha = A_(i+1, i);
        float ssq = 0.f;
        for (int k = i+2; k <= n; k++){ float v = A_(k,i); ssq += v*v; }
        float xnorm = sqrtf(ssq);
        float taui;
        if (xnorm == 0.f){
            taui = 0.f;
        } else {
            float beta = -f_sign(slapy2(alpha, xnorm), alpha);
            taui = (beta - alpha) / beta;
            float sc = 1.f / (alpha - beta);
            for (int k = i+2; k <= n; k++) A_(k,i) *= sc;   // all lanes same value
            alpha = beta;
        }
        ee[i] = alpha;
        if (taui != 0.f){
            A_(i+1, i) = 1.f;
            const int n2 = n - i;
            // parallel ssymv 'L': lane l2 computes px[l2], contribution order
            // identical to LAPACK's interleaved j-loop:
            //   j=1..l2-1 terms, then diagonal, then taui*temp2.
            if (lane >= 1 && lane <= n2){
                const int l2 = lane;
                float p = 0.f;
                for (int j = 1; j <= l2-1; j++)
                    p = p + (taui * A_(i+j, i)) * A_(i+l2, i+j);
                p = p + (taui * A_(i+l2, i)) * A_(i+l2, i+l2);
                float temp2 = 0.f;
                for (int ii2 = l2+1; ii2 <= n2; ii2++)
                    temp2 = temp2 + A_(i+ii2, i+l2) * A_(i+ii2, i);
                p = p + taui * temp2;
                px[l2] = p;
            }
            // sdot (serial order, redundant on all lanes)
            float dot = 0.f;
            for (int j = 1; j <= n2; j++) dot = dot + px[j] * A_(i+j, i);
            float alpha2 = -0.5f * taui * dot;
            if (lane >= 1 && lane <= n2)
                px[lane] = px[lane] + alpha2 * A_(i+lane, i);
            // parallel ssyr2 'L': lane = column j; per-element update identical
            if (lane >= 1 && lane <= n2){
                const int j = lane;
                float xj = A_(i+j, i);
                float yj = px[j];
                if (xj != 0.f || yj != 0.f){
                    float temp1 = -yj;
                    float temp2 = -xj;
                    for (int ii2 = j; ii2 <= n2; ii2++){
                        A_(i+ii2, i+j) = A_(i+ii2, i+j)
                                       + A_(i+ii2, i)*temp1 + px[ii2]*temp2;
                    }
                }
            }
            A_(i+1, i) = ee[i];
        }
        dd[i] = A_(i, i);
        tt[i] = taui;
    }
    dd[n] = A_(n, n);

    // Z = I (parallel)
    for (int idx = lane; idx < 100; idx += 64)
        Zz[idx] = ((idx % 10) == (idx / 10)) ? 1.f : 0.f;

    // ---------------- ssteqr 'I' ----------------
    const float eps    = 0x1.0p-24f;
    const float eps2   = 0x1.0p-48f;
    const float safmin = 0x1.0p-126f;
    const int nmaxit = n * 30;
    int jtot = 0;
    int l1 = 1;

    while (true){
        if (l1 > n) break;
        if (l1 > 1) ee[l1-1] = 0.f;
        int m = n;
        if (l1 <= n-1){
            for (m = l1; m <= n-1; m++){
                float tst = fabsf(ee[m]);
                if (tst == 0.f) break;
                if (tst <= (sqrtf(fabsf(dd[m])) * sqrtf(fabsf(dd[m+1]))) * eps){
                    ee[m] = 0.f;
                    break;
                }
            }
        }
        int l = l1;
        int lsv = l;
        int lend = m;
        int lendsv = lend;
        l1 = m + 1;
        if (lend == l) continue;

        float anorm = 0.f;
        for (int k = l; k <= lend; k++)   anorm = fmaxf(anorm, fabsf(dd[k]));
        for (int k = l; k <= lend-1; k++) anorm = fmaxf(anorm, fabsf(ee[k]));
        if (anorm == 0.f) continue;

        if (fabsf(dd[lend]) < fabsf(dd[l])){
            lend = lsv;
            l = lendsv;
        }

        if (lend > l){
            // -------- QL --------
            while (true){
                int mq = lend;
                if (l != lend){
                    for (int t2 = l; t2 <= lend-1; t2++){
                        float ev = fabsf(ee[t2]);
                        if (ev*ev <= (eps2*fabsf(dd[t2]))*fabsf(dd[t2+1]) + safmin){
                            mq = t2; break;
                        }
                    }
                }
                if (mq < lend) ee[mq] = 0.f;
                float p = dd[l];
                if (mq == l){
                    dd[l] = p;
                    l = l + 1;
                    if (l <= lend) continue;
                    break;
                }
                if (mq == l+1){
                    float rt1, rt2, cc, ss;
                    slaev2(dd[l], ee[l], dd[l+1], &rt1, &rt2, &cc, &ss);
                    wk[l] = cc; wk[n-1+l] = ss;
                    if (lane >= 1 && lane <= n){
                        float temp = Z_(lane, l+1);
                        Z_(lane, l+1) = cc*temp - ss*Z_(lane, l);
                        Z_(lane, l)   = ss*temp + cc*Z_(lane, l);
                    }
                    dd[l] = rt1; dd[l+1] = rt2; ee[l] = 0.f;
                    l += 2;
                    if (l <= lend) continue;
                    break;
                }
                if (jtot == nmaxit) break;
                jtot++;
                float g = (dd[l+1] - p) / (2.f * ee[l]);
                float r = slapy2(g, 1.f);
                g = dd[mq] - p + (ee[l] / (g + f_sign(r, g)));
                float ss = 1.f, cc = 1.f;
                p = 0.f;
                for (int i2 = mq-1; i2 >= l; i2--){
                    float ff = ss * ee[i2];
                    float bb = cc * ee[i2];
                    slartg(g, ff, &cc, &ss, &r);
                    if (i2 != mq-1) ee[i2+1] = r;
                    g = dd[i2+1] - p;
                    r = (dd[i2] - g)*ss + 2.f*cc*bb;
                    p = ss*r;
                    dd[i2+1] = g + p;
                    g = cc*r - bb;
                    wk[i2] = cc;
                    wk[n-1+i2] = -ss;
                }
                // slasr 'R','V','B' — rows lane-parallel, per-row order identical
                for (int jj = mq-1; jj >= l; jj--){
                    float ct = wk[jj], st = wk[n-1+jj];
                    if (ct != 1.f || st != 0.f){
                        if (lane >= 1 && lane <= n){
                            float temp = Z_(lane, jj+1);
                            Z_(lane, jj+1) = ct*temp - st*Z_(lane, jj);
                            Z_(lane, jj)   = st*temp + ct*Z_(lane, jj);
                        }
                    }
                }
                dd[l] = dd[l] - p;
                ee[l] = g;
            }
        } else {
            // -------- QR --------
            while (true){
                int mq = lend;
                if (l != lend){
                    for (int t2 = l; t2 >= lend+1; t2--){
                        float ev = fabsf(ee[t2-1]);
                        if (ev*ev <= (eps2*fabsf(dd[t2]))*fabsf(dd[t2-1]) + safmin){
                            mq = t2; break;
                        }
                    }
                }
                if (mq > lend) ee[mq-1] = 0.f;
                float p = dd[l];
                if (mq == l){
                    dd[l] = p;
                    l = l - 1;
                    if (l >= lend) continue;
                    break;
                }
                if (mq == l-1){
                    float rt1, rt2, cc, ss;
                    slaev2(dd[l-1], ee[l-1], dd[l], &rt1, &rt2, &cc, &ss);
                    wk[mq] = cc; wk[n-1+mq] = ss;
                    if (lane >= 1 && lane <= n){
                        float temp = Z_(lane, l);
                        Z_(lane, l)   = cc*temp - ss*Z_(lane, l-1);
                        Z_(lane, l-1) = ss*temp + cc*Z_(lane, l-1);
                    }
                    dd[l-1] = rt1; dd[l] = rt2; ee[l-1] = 0.f;
                    l -= 2;
                    if (l >= lend) continue;
                    break;
                }
                if (jtot == nmaxit) break;
                jtot++;
                float g = (dd[l-1] - p) / (2.f * ee[l-1]);
                float r = slapy2(g, 1.f);
                g = dd[mq] - p + (ee[l-1] / (g + f_sign(r, g)));
                float ss = 1.f, cc = 1.f;
                p = 0.f;
                for (int i2 = mq; i2 <= l-1; i2++){
                    float ff = ss * ee[i2];
                    float bb = cc * ee[i2];
                    slartg(g, ff, &cc, &ss, &r);
                    if (i2 != mq) ee[i2-1] = r;
                    g = dd[i2] - p;
                    r = (dd[i2+1] - g)*ss + 2.f*cc*bb;
                    p = ss*r;
                    dd[i2] = g + p;
                    g = cc*r - bb;
                    wk[i2] = cc;
                    wk[n-1+i2] = ss;
                }
                // slasr 'R','V','F' — rows lane-parallel
                for (int jj = mq; jj <= l-1; jj++){
                    float ct = wk[jj], st = wk[n-1+jj];
                    if (ct != 1.f || st != 0.f){
                        if (lane >= 1 && lane <= n){
                            float temp = Z_(lane, jj+1);
                            Z_(lane, jj+1) = ct*temp - st*Z_(lane, jj);
                            Z_(lane, jj)   = st*temp + ct*Z_(lane, jj);
                        }
                    }
                }
                dd[l] = dd[l] - p;
                ee[l-1] = g;
            }
        }
        if (jtot < nmaxit) continue;
        break;
    }

    // ---------------- argmax instead of full sort ----------------
    // (ascending sort's position n == maximum; column swaps don't change signs)
    int kmax = 1;
    {
        float p = dd[1];
        for (int j = 2; j <= n; j++){
            if (dd[j] > p){ p = dd[j]; kmax = j; }
        }
    }

    // ---------------- sormtr 'L','L','N' on the single argmax column ------
    if (lane >= 1 && lane <= n) vcol[lane] = Z_(lane, kmax);
    for (int i = n-1; i >= 1; i--){
        float taui = tt[i];
        if (taui != 0.f){
            float s1 = vcol[i+1];
            for (int r2 = i+2; r2 <= n; r2++) s1 = s1 + A_(r2, i) * vcol[r2];
            s1 = taui * s1;
            vcol[i+1] = vcol[i+1] - s1;                   // all lanes same value
            if (lane >= i+2 && lane <= n)
                vcol[lane] = vcol[lane] - A_(lane, i) * s1;
        }
    }
}

// ======================= Kernel 2: D, eigh, outputs =======================
__global__ __launch_bounds__(64) void k2_eig(
        const float* __restrict__ partial, const float* __restrict__ tmpl,
        float* __restrict__ out, int cblk)
{
    __shared__ float SS[65];
    __shared__ float Aa[100];
    __shared__ float Zz[100];
    __shared__ float dd[11], ee[11], tt[11], wk[20], px[11], vcol[11];
    const int lane = threadIdx.x;
    const int b = blockIdx.x;

    for (int i = lane; i < 65; i += 64){
        float s = 0.f;
        for (int p = 0; p < cblk; p++)
            s += partial[(size_t)(b*cblk + p)*65 + i];
        SS[i] = s;
    }
    __syncthreads();

    // D[t][s] = S2[t,s] - S1[t]*S1[s]/C   (exactly symmetric)
    for (int idx = lane; idx < 100; idx += 64){
        int t = idx % 10, s2 = idx / 10;
        int lo = t < s2 ? t : s2, hi = t < s2 ? s2 : t;
        int pk = 10*lo - (lo*(lo-1))/2 + (hi - lo);
        Aa[s2*10 + t] = SS[10 + pk] - SS[t]*SS[s2]*(1.0f/2048.0f);
    }
    __syncthreads();

    eig10_wave(lane, Aa, Zz, dd, ee, tt, wk, px, vcol);
    __syncthreads();

    if (lane >= 1 && lane <= NTMP)
        out[(size_t)NB*NHW + (size_t)b*NTMP + (lane-1)] = vcol[lane];

    for (int i = lane; i < NHW; i += 64){
        float m2 = 0.f;
        #pragma unroll
        for (int t = 0; t < NTMP; t++) m2 += vcol[t+1] * tmpl[t*NHW + i];
        out[(size_t)b*NHW + i] = m2;
    }
}

// ============================== launcher ==================================
extern "C" void kernel_launch(void* const* d_in, const int* in_sizes, int n_in,
                              void* d_out, int out_size, void* d_ws, size_t ws_size,
                              hipStream_t stream)
{
    const float* x    = (const float*)d_in[0];
    const float* tmpl = (const float*)d_in[1];
    float* out = (float*)d_out;
    float* partial = (float*)d_ws;

    if (ws_size >= (size_t)NB*4*65*sizeof(float)){
        // NCPT=2: 512 channels/block, 4 blocks/batch -> grid 256
        k1_partials<2><<<dim3(NB*4), dim3(256), 0, stream>>>(x, tmpl, partial);
        k2_eig<<<dim3(NB), dim3(64), 0, stream>>>(partial, tmpl, out, 4);
    } else {
        // fallback: whole batch per block
        k1_partials<8><<<dim3(NB), dim3(256), 0, stream>>>(x, tmpl, partial);
        k2_eig<<<dim3(NB), dim3(64), 0, stream>>>(partial, tmpl, out, 1);
    }
}